// Round 5
// baseline (952.986 us; speedup 1.0000x reference)
//
#include <hip/hip_runtime.h>

typedef float f32x4 __attribute__((ext_vector_type(4)));
typedef unsigned char uchar;
typedef long i64;

#define KEPS 1e-8f
#define BM 256
#define BN 128

// ---------------- 1) row L2-normalize: fp32 norms + fp8 e4m3 copy -----------
__global__ __launch_bounds__(256) void k_normalize(
    const float* __restrict__ in, uchar* __restrict__ xq,
    float* __restrict__ norms, unsigned long long* __restrict__ best,
    float* __restrict__ psum, int D)
{
    const int row = blockIdx.x;
    const int t = threadIdx.x;
    const float4* inr = (const float4*)(in + (size_t)row * D);
    float4 v = inr[t];                       // D=1024 -> 256 float4
    float ss = v.x*v.x + v.y*v.y + v.z*v.z + v.w*v.w;
    for (int off = 32; off; off >>= 1) ss += __shfl_down(ss, off);
    __shared__ float red[4];
    const int lane = t & 63, wave = t >> 6;
    if (lane == 0) red[wave] = ss;
    __syncthreads();
    const float total = red[0] + red[1] + red[2] + red[3];
    const float nrm = sqrtf(total);
    const float inv = 1.0f / fmaxf(nrm, KEPS);
    // pack 4 floats -> 4 fp8 e4m3 bytes (OCP, HW saturating convert)
    unsigned r = 0;
    r = __builtin_amdgcn_cvt_pk_fp8_f32(v.x * inv, v.y * inv, r, 0);
    r = __builtin_amdgcn_cvt_pk_fp8_f32(v.z * inv, v.w * inv, r, 1);
    ((unsigned*)(xq + (size_t)row * D))[t] = r;
    if (t == 0) {
        norms[row] = nrm;
        best[row] = 0ull;                    // any real packed key beats 0
    }
    if (row < 256 && t == 1) psum[row * 16] = 0.0f;   // cache-line-padded partials
}

__device__ __forceinline__ unsigned long long pack_key(float v, unsigned idx)
{
    unsigned ub = __float_as_uint(v);
    ub = (ub & 0x80000000u) ? ~ub : (ub | 0x80000000u); // monotonic map
    return ((unsigned long long)ub << 32) | (unsigned long long)(~idx);
}

// ---------------- 2) x x^T triangular fp8 GEMM with fused argmax ------------
// LDS-FREE, BARRIER-FREE: each wave owns a 128x64 output tile (acc 8x4 of
// f32x4) and loads its MFMA fragments directly global->VGPR with per-lane
// address row*D + quad*8 and the K-step as an *immediate* offset (full
// unroll). Depth-1 register ping-pong: prefetch step s+1 during MFMA of s.
// Fragment mapping identical to the LDS version: k = step*32 + quad*8 + byte,
// m/n = tile*16 + (lane&15).  L1 absorbs the 2x reuse of each 64B line by
// adjacent K-steps; A/B panels shared 2-way across waves via L1/L2.
// Triangular covering: blocks with bx >= 2*by; row-pass + col-pass covers
// every unordered pair; duplicates harmless under atomicMax.
__global__ __launch_bounds__(256, 2) void k_gemm_argmax(
    const uchar* __restrict__ xq, unsigned long long* __restrict__ best,
    int N, int D, int TX)
{
    // triangular mapping: p -> (by, bx), bx >= 2*by ; off(by) = by*(TX+1-by)
    const int p = blockIdx.x;
    const float c1 = (float)(TX + 1);
    int by = (int)((c1 - sqrtf(c1 * c1 - 4.0f * (float)p)) * 0.5f);
    while (by > 0 && p < by * (TX + 1 - by)) --by;
    while (p >= (by + 1) * (TX - by)) ++by;
    const int bx = 2 * by + (p - by * (TX + 1 - by));

    const int t    = threadIdx.x;
    const int lane = t & 63;
    const int wave = t >> 6;
    const int quad = lane >> 4;
    const int c16  = lane & 15;
    const int wrow = (wave >> 1) * 128;      // wave's row-half of the 256
    const int wcol = (wave & 1) * 64;        // wave's col-half of the 128
    const int m0   = by * BM;
    const int n0   = bx * BN;

    f32x4 acc[8][4] = {};

    // per-lane base byte offsets (max ~16.7M, fits int)
    int aoff[8], boff[4];
    #pragma unroll
    for (int i = 0; i < 8; ++i)
        aoff[i] = (m0 + wrow + i * 16 + c16) * 1024 + quad * 8;
    #pragma unroll
    for (int j = 0; j < 4; ++j)
        boff[j] = (n0 + wcol + j * 16 + c16) * 1024 + quad * 8;

    i64 aR[2][8], bR[2][4];
    #pragma unroll
    for (int i = 0; i < 8; ++i) aR[0][i] = *(const i64*)(xq + aoff[i]);
    #pragma unroll
    for (int j = 0; j < 4; ++j) bR[0][j] = *(const i64*)(xq + boff[j]);

    #pragma unroll
    for (int ks = 0; ks < 32; ++ks) {        // K = 32 steps of 32
        const int cur = ks & 1;
        if (ks + 1 < 32) {
            const int ko = (ks + 1) * 32;    // compile-time after unroll
            #pragma unroll
            for (int i = 0; i < 8; ++i)
                aR[cur ^ 1][i] = *(const i64*)(xq + aoff[i] + ko);
            #pragma unroll
            for (int j = 0; j < 4; ++j)
                bR[cur ^ 1][j] = *(const i64*)(xq + boff[j] + ko);
        }
        #pragma unroll
        for (int i = 0; i < 8; ++i)
            #pragma unroll
            for (int j = 0; j < 4; ++j)
                acc[i][j] = __builtin_amdgcn_mfma_f32_16x16x32_fp8_fp8(
                    aR[cur][i], bR[cur][j], acc[i][j], 0, 0, 0);
    }

    // ---- row-wise argmax (this wave's 128 rows, over its 64 cols) ----
    // C/D layout (m89-verified, dtype-independent): col = lane&15, row = quad*4 + reg.
    #pragma unroll
    for (int i = 0; i < 8; ++i) {
        #pragma unroll
        for (int r = 0; r < 4; ++r) {
            const int grow = m0 + wrow + i * 16 + quad * 4 + r;
            float v = -3.0f; unsigned c = 0xFFFFFFFFu;
            #pragma unroll
            for (int j = 0; j < 4; ++j) {
                const int col = n0 + wcol + j * 16 + c16;
                const float val = acc[i][j][r];
                if (col != grow && (val > v || (val == v && (unsigned)col < c))) {
                    v = val; c = (unsigned)col;
                }
            }
            // reduce across the quad's 16 lanes (one row lives in one quad)
            for (int off = 8; off; off >>= 1) {
                const float    ov = __shfl_xor(v, off);
                const unsigned oc = (unsigned)__shfl_xor((int)c, off);
                if (ov > v || (ov == v && oc < c)) { v = ov; c = oc; }
            }
            if (c16 == 0) atomicMax(best + grow, pack_key(v, c));
        }
    }

    // ---- col-wise argmax (this wave's 64 cols, over its 128 rows) ----
    #pragma unroll
    for (int j = 0; j < 4; ++j) {
        const int gcol = n0 + wcol + j * 16 + c16;
        float v = -3.0f; unsigned c = 0xFFFFFFFFu;
        #pragma unroll
        for (int i = 0; i < 8; ++i) {
            #pragma unroll
            for (int r = 0; r < 4; ++r) {
                const int grow = m0 + wrow + i * 16 + quad * 4 + r;
                const float val = acc[i][j][r];
                if (grow != gcol && (val > v || (val == v && (unsigned)grow < c))) {
                    v = val; c = (unsigned)grow;
                }
            }
        }
        // reduce across the 4 quads (lanes sharing c16): xor 16, 32
        for (int off = 32; off >= 16; off >>= 1) {
            const float    ov = __shfl_xor(v, off);
            const unsigned oc = (unsigned)__shfl_xor((int)c, off);
            if (ov > v || (ov == v && oc < c)) { v = ov; c = oc; }
        }
        if (quad == 0) atomicMax(best + gcol, pack_key(v, c));
    }
}

// ---------------- 3) pairwise distance + log -> 256 padded partials ---------
__global__ __launch_bounds__(256) void k_dist(
    const float* __restrict__ in, const float* __restrict__ norms,
    const unsigned long long* __restrict__ best, float* __restrict__ psum, int D)
{
    const int row = blockIdx.x;
    const int t = threadIdx.x;
    const unsigned long long key = best[row];
    const int nb = (int)(~(unsigned)key);        // recover neighbor index
    const float invi = 1.0f / fmaxf(norms[row], KEPS);
    const float invj = 1.0f / fmaxf(norms[nb], KEPS);
    const float4* xi = (const float4*)(in + (size_t)row * D);
    const float4* xj = (const float4*)(in + (size_t)nb * D);
    const float4 a = xi[t], b = xj[t];
    const float dx = a.x * invi - b.x * invj + KEPS;
    const float dy = a.y * invi - b.y * invj + KEPS;
    const float dz = a.z * invi - b.z * invj + KEPS;
    const float dw = a.w * invi - b.w * invj + KEPS;
    float ss = dx*dx + dy*dy + dz*dz + dw*dw;
    for (int off = 32; off; off >>= 1) ss += __shfl_down(ss, off);
    __shared__ float red[4];
    const int lane = t & 63, wave = t >> 6;
    if (lane == 0) red[wave] = ss;
    __syncthreads();
    if (t == 0) {
        const float tot = red[0] + red[1] + red[2] + red[3];
        // scatter over 256 cache-line-padded slots: 64 atomics/slot, no hotspot
        atomicAdd(psum + (row & 255) * 16, logf(sqrtf(tot) + KEPS));
    }
}

// ---------------- 4) finalize: reduce 256 partials --------------------------
__global__ void k_final(const float* __restrict__ psum, float* __restrict__ out, float invN)
{
    const int t = threadIdx.x;                   // 64 threads
    float s = psum[t * 16] + psum[(t + 64) * 16]
            + psum[(t + 128) * 16] + psum[(t + 192) * 16];
    for (int off = 32; off; off >>= 1) s += __shfl_down(s, off);
    if (t == 0) out[0] = -s * invN;
}

extern "C" void kernel_launch(void* const* d_in, const int* in_sizes, int n_in,
                              void* d_out, int out_size, void* d_ws, size_t ws_size,
                              hipStream_t stream)
{
    const float* in = (const float*)d_in[0];
    const int D = 1024;
    const int N = in_sizes[0] / D;               // 16384

    char* ws = (char*)d_ws;
    uchar* xq = (uchar*)ws;                                      // N*D     = 16 MiB
    size_t off = (size_t)N * D;
    float* norms = (float*)(ws + off);           off += (size_t)N * 4;
    unsigned long long* best = (unsigned long long*)(ws + off); off += (size_t)N * 8;
    float* psum = (float*)(ws + off);            // 256 slots x 16 floats = 16 KiB
    float* out = (float*)d_out;

    k_normalize<<<N, 256, 0, stream>>>(in, xq, norms, best, psum, D);
    const int TY = N / BM;                       // 64 row-tiles
    const int TX = N / BN;                       // 128 col-tiles
    int P = 0;
    for (int by = 0; by < TY; ++by) P += TX - 2 * by;   // 4160 blocks
    k_gemm_argmax<<<P, 256, 0, stream>>>(xq, best, N, D, TX);
    k_dist<<<N, 256, 0, stream>>>(in, norms, best, psum, D);
    k_final<<<1, 64, 0, stream>>>(psum, out, 1.0f / (float)N);
}

// Round 6
// 866.429 us; speedup vs baseline: 1.0999x; 1.0999x over previous
//
#include <hip/hip_runtime.h>

typedef float f32x4 __attribute__((ext_vector_type(4)));
typedef unsigned char uchar;
typedef long i64;

#define KEPS 1e-8f
#define BM 256
#define BN 128

// Tiled fp8 layout: for row panel P (16 rows), K-step ks (32 k-elems), the
// 64-lane MFMA fragment is contiguous:
//   byte(P, ks, quad, c16, b) = P*16384 + ks*512 + (quad*16 + c16)*8 + b
// where row = P*16 + c16 and k = ks*32 + quad*8 + b.
// A wave's fragment load is then 64 lanes x 8B = 512B contiguous (8 lines).

// ---------------- 1) panel L2-normalize -> tiled fp8 + fp32 norms -----------
// One block per 16-row panel. Thread t: row r = t>>4, k-range q*64..q*64+63
// (q = t&15). 16-lane shuffle reduction for row sums.
__global__ __launch_bounds__(256) void k_normalize(
    const float* __restrict__ in, uchar* __restrict__ xq,
    float* __restrict__ norms, unsigned long long* __restrict__ best,
    float* __restrict__ psum)
{
    const int panel = blockIdx.x;
    const int t = threadIdx.x;
    const int r = t >> 4;               // row within panel
    const int q = t & 15;               // 64-element chunk within row
    const int row = panel * 16 + r;

    const float4* src = (const float4*)(in + (size_t)row * 1024 + q * 64);
    float4 f[16];
    float ss = 0.0f;
    #pragma unroll
    for (int u = 0; u < 16; ++u) {
        f[u] = src[u];
        ss += f[u].x*f[u].x + f[u].y*f[u].y + f[u].z*f[u].z + f[u].w*f[u].w;
    }
    // reduce across the 16 lanes sharing this row (xor<16 stays in group)
    for (int off = 8; off; off >>= 1) ss += __shfl_xor(ss, off);
    const float nrm = sqrtf(ss);
    const float inv = 1.0f / fmaxf(nrm, KEPS);

    // emit 64 fp8 bytes as 8 chunks of 8B in tiled order
    uchar* dst = xq + (size_t)panel * 16384;
    #pragma unroll
    for (int half = 0; half < 2; ++half) {       // ks = 2q + half
        #pragma unroll
        for (int quad = 0; quad < 4; ++quad) {
            const int fo = half * 8 + quad * 2;  // float4 index of k-group start
            unsigned lo = 0, hi = 0;
            lo = __builtin_amdgcn_cvt_pk_fp8_f32(f[fo].x * inv, f[fo].y * inv, lo, 0);
            lo = __builtin_amdgcn_cvt_pk_fp8_f32(f[fo].z * inv, f[fo].w * inv, lo, 1);
            hi = __builtin_amdgcn_cvt_pk_fp8_f32(f[fo+1].x * inv, f[fo+1].y * inv, hi, 0);
            hi = __builtin_amdgcn_cvt_pk_fp8_f32(f[fo+1].z * inv, f[fo+1].w * inv, hi, 1);
            const unsigned long long v = (unsigned long long)lo | ((unsigned long long)hi << 32);
            *(unsigned long long*)(dst + (2*q + half) * 512 + (quad * 16 + r) * 8) = v;
        }
    }
    if (q == 0) {
        norms[row] = nrm;
        best[row] = 0ull;                        // any real packed key beats 0
    }
    if (panel == 0) psum[t * 16] = 0.0f;         // 256 cache-line-padded partials
}

__device__ __forceinline__ unsigned long long pack_key(float v, unsigned idx)
{
    unsigned ub = __float_as_uint(v);
    ub = (ub & 0x80000000u) ? ~ub : (ub | 0x80000000u); // monotonic map
    return ((unsigned long long)ub << 32) | (unsigned long long)(~idx);
}

// ---------------- 2) x x^T triangular fp8 GEMM with fused argmax ------------
// LDS-free, barrier-free. Each wave owns 128x64 (acc 8x4 of f32x4); fragments
// loaded directly global->VGPR from the tiled layout: every load is 512B
// lane-contiguous (8 lines, fully coalesced). Depth-1 register ping-pong:
// prefetch step ks+1 while MFMA-ing step ks. Triangular covering bx >= 2*by;
// row-pass + col-pass covers every unordered pair (dups harmless, atomicMax).
__global__ __launch_bounds__(256, 2) void k_gemm_argmax(
    const uchar* __restrict__ xq, unsigned long long* __restrict__ best,
    int TX)
{
    // triangular mapping: p -> (by, bx), bx >= 2*by ; off(by) = by*(TX+1-by)
    const int p = blockIdx.x;
    const float c1 = (float)(TX + 1);
    int by = (int)((c1 - sqrtf(c1 * c1 - 4.0f * (float)p)) * 0.5f);
    while (by > 0 && p < by * (TX + 1 - by)) --by;
    while (p >= (by + 1) * (TX - by)) ++by;
    const int bx = 2 * by + (p - by * (TX + 1 - by));

    const int t    = threadIdx.x;
    const int lane = t & 63;
    const int wave = t >> 6;
    const int quad = lane >> 4;
    const int c16  = lane & 15;
    const int wrow = (wave >> 1) * 128;      // wave's row-half of the 256
    const int wcol = (wave & 1) * 64;        // wave's col-half of the 128
    const int m0   = by * BM;
    const int n0   = bx * BN;

    f32x4 acc[8][4] = {};

    // fragment base pointers (panel-granular)
    const uchar* aptr = xq + (size_t)((m0 + wrow) >> 4) * 16384 + lane * 8;
    const uchar* bptr = xq + (size_t)((n0 + wcol) >> 4) * 16384 + lane * 8;

    i64 aF[2][8], bF[2][4];
    #pragma unroll
    for (int i = 0; i < 8; ++i) aF[0][i] = *(const i64*)(aptr + i * 16384);
    #pragma unroll
    for (int j = 0; j < 4; ++j) bF[0][j] = *(const i64*)(bptr + j * 16384);

    #pragma unroll
    for (int ks = 0; ks < 32; ++ks) {        // K = 32 steps of 32
        const int cur = ks & 1;
        if (ks + 1 < 32) {
            const int ko = (ks + 1) * 512;   // compile-time after unroll
            #pragma unroll
            for (int i = 0; i < 8; ++i)
                aF[cur ^ 1][i] = *(const i64*)(aptr + i * 16384 + ko);
            #pragma unroll
            for (int j = 0; j < 4; ++j)
                bF[cur ^ 1][j] = *(const i64*)(bptr + j * 16384 + ko);
        }
        #pragma unroll
        for (int i = 0; i < 8; ++i)
            #pragma unroll
            for (int j = 0; j < 4; ++j)
                acc[i][j] = __builtin_amdgcn_mfma_f32_16x16x32_fp8_fp8(
                    aF[cur][i], bF[cur][j], acc[i][j], 0, 0, 0);
    }

    // ---- row-wise argmax (this wave's 128 rows, over its 64 cols) ----
    // C/D layout (m89-verified, dtype-independent): col = lane&15, row = quad*4 + reg.
    #pragma unroll
    for (int i = 0; i < 8; ++i) {
        #pragma unroll
        for (int r = 0; r < 4; ++r) {
            const int grow = m0 + wrow + i * 16 + quad * 4 + r;
            float v = -3.0f; unsigned c = 0xFFFFFFFFu;
            #pragma unroll
            for (int j = 0; j < 4; ++j) {
                const int col = n0 + wcol + j * 16 + c16;
                const float val = acc[i][j][r];
                if (col != grow && (val > v || (val == v && (unsigned)col < c))) {
                    v = val; c = (unsigned)col;
                }
            }
            // reduce across the quad's 16 lanes (one row lives in one quad)
            for (int off = 8; off; off >>= 1) {
                const float    ov = __shfl_xor(v, off);
                const unsigned oc = (unsigned)__shfl_xor((int)c, off);
                if (ov > v || (ov == v && oc < c)) { v = ov; c = oc; }
            }
            if (c16 == 0) atomicMax(best + grow, pack_key(v, c));
        }
    }

    // ---- col-wise argmax (this wave's 64 cols, over its 128 rows) ----
    #pragma unroll
    for (int j = 0; j < 4; ++j) {
        const int gcol = n0 + wcol + j * 16 + c16;
        float v = -3.0f; unsigned c = 0xFFFFFFFFu;
        #pragma unroll
        for (int i = 0; i < 8; ++i) {
            #pragma unroll
            for (int r = 0; r < 4; ++r) {
                const int grow = m0 + wrow + i * 16 + quad * 4 + r;
                const float val = acc[i][j][r];
                if (grow != gcol && (val > v || (val == v && (unsigned)grow < c))) {
                    v = val; c = (unsigned)grow;
                }
            }
        }
        // reduce across the 4 quads (lanes sharing c16): xor 16, 32
        for (int off = 32; off >= 16; off >>= 1) {
            const float    ov = __shfl_xor(v, off);
            const unsigned oc = (unsigned)__shfl_xor((int)c, off);
            if (ov > v || (ov == v && oc < c)) { v = ov; c = oc; }
        }
        if (quad == 0) atomicMax(best + gcol, pack_key(v, c));
    }
}

// ---------------- 3) pairwise distance + log -> 256 padded partials ---------
__global__ __launch_bounds__(256) void k_dist(
    const float* __restrict__ in, const float* __restrict__ norms,
    const unsigned long long* __restrict__ best, float* __restrict__ psum, int D)
{
    const int row = blockIdx.x;
    const int t = threadIdx.x;
    const unsigned long long key = best[row];
    const int nb = (int)(~(unsigned)key);        // recover neighbor index
    const float invi = 1.0f / fmaxf(norms[row], KEPS);
    const float invj = 1.0f / fmaxf(norms[nb], KEPS);
    const float4* xi = (const float4*)(in + (size_t)row * D);
    const float4* xj = (const float4*)(in + (size_t)nb * D);
    const float4 a = xi[t], b = xj[t];
    const float dx = a.x * invi - b.x * invj + KEPS;
    const float dy = a.y * invi - b.y * invj + KEPS;
    const float dz = a.z * invi - b.z * invj + KEPS;
    const float dw = a.w * invi - b.w * invj + KEPS;
    float ss = dx*dx + dy*dy + dz*dz + dw*dw;
    for (int off = 32; off; off >>= 1) ss += __shfl_down(ss, off);
    __shared__ float red[4];
    const int lane = t & 63, wave = t >> 6;
    if (lane == 0) red[wave] = ss;
    __syncthreads();
    if (t == 0) {
        const float tot = red[0] + red[1] + red[2] + red[3];
        // scatter over 256 cache-line-padded slots: 64 atomics/slot, no hotspot
        atomicAdd(psum + (row & 255) * 16, logf(sqrtf(tot) + KEPS));
    }
}

// ---------------- 4) finalize: reduce 256 partials --------------------------
__global__ void k_final(const float* __restrict__ psum, float* __restrict__ out, float invN)
{
    const int t = threadIdx.x;                   // 64 threads
    float s = psum[t * 16] + psum[(t + 64) * 16]
            + psum[(t + 128) * 16] + psum[(t + 192) * 16];
    for (int off = 32; off; off >>= 1) s += __shfl_down(s, off);
    if (t == 0) out[0] = -s * invN;
}

extern "C" void kernel_launch(void* const* d_in, const int* in_sizes, int n_in,
                              void* d_out, int out_size, void* d_ws, size_t ws_size,
                              hipStream_t stream)
{
    const float* in = (const float*)d_in[0];
    const int D = 1024;
    const int N = in_sizes[0] / D;               // 16384

    char* ws = (char*)d_ws;
    uchar* xq = (uchar*)ws;                                      // N*D     = 16 MiB (tiled)
    size_t off = (size_t)N * D;
    float* norms = (float*)(ws + off);           off += (size_t)N * 4;
    unsigned long long* best = (unsigned long long*)(ws + off); off += (size_t)N * 8;
    float* psum = (float*)(ws + off);            // 256 slots x 16 floats = 16 KiB
    float* out = (float*)d_out;

    k_normalize<<<N / 16, 256, 0, stream>>>(in, xq, norms, best, psum);
    const int TY = N / BM;                       // 64 row-tiles
    const int TX = N / BN;                       // 128 col-tiles
    int P = 0;
    for (int by = 0; by < TY; ++by) P += TX - 2 * by;   // 4160 blocks
    k_gemm_argmax<<<P, 256, 0, stream>>>(xq, best, TX);
    k_dist<<<N, 256, 0, stream>>>(in, norms, best, psum, D);
    k_final<<<1, 64, 0, stream>>>(psum, out, 1.0f / (float)N);
}

// Round 7
// 528.788 us; speedup vs baseline: 1.8022x; 1.6385x over previous
//
#include <hip/hip_runtime.h>

typedef float f32x4 __attribute__((ext_vector_type(4)));
typedef unsigned char uchar;
typedef long i64;

#define KEPS 1e-8f
#define BM 128
#define BN 128
#define BK 128   // fp8 bytes == elements; 8 K-iterations over D=1024

// ---------------- 1) row L2-normalize: fp32 norms + fp8 e4m3 copy -----------
__global__ __launch_bounds__(256) void k_normalize(
    const float* __restrict__ in, uchar* __restrict__ xq,
    float* __restrict__ norms, unsigned long long* __restrict__ best,
    float* __restrict__ psum, int D)
{
    const int row = blockIdx.x;
    const int t = threadIdx.x;
    const float4* inr = (const float4*)(in + (size_t)row * D);
    float4 v = inr[t];                       // D=1024 -> 256 float4
    float ss = v.x*v.x + v.y*v.y + v.z*v.z + v.w*v.w;
    for (int off = 32; off; off >>= 1) ss += __shfl_down(ss, off);
    __shared__ float red[4];
    const int lane = t & 63, wave = t >> 6;
    if (lane == 0) red[wave] = ss;
    __syncthreads();
    const float total = red[0] + red[1] + red[2] + red[3];
    const float nrm = sqrtf(total);
    const float inv = 1.0f / fmaxf(nrm, KEPS);
    unsigned r = 0;
    r = __builtin_amdgcn_cvt_pk_fp8_f32(v.x * inv, v.y * inv, r, 0);
    r = __builtin_amdgcn_cvt_pk_fp8_f32(v.z * inv, v.w * inv, r, 1);
    ((unsigned*)(xq + (size_t)row * D))[t] = r;
    if (t == 0) {
        norms[row] = nrm;
        best[row] = 0ull;                    // any real packed key beats 0
    }
    if (row < 256 && t == 1) psum[row * 16] = 0.0f;   // cache-line-padded partials
}

__device__ __forceinline__ unsigned long long pack_key(float v, unsigned idx)
{
    unsigned ub = __float_as_uint(v);
    ub = (ub & 0x80000000u) ? ~ub : (ub | 0x80000000u); // monotonic map
    return ((unsigned long long)ub << 32) | (unsigned long long)(~idx);
}

// ---------------- 2) x x^T triangular fp8 GEMM, DOUBLE-BUFFERED LDS ---------
// BM=BN=128, BK=128, 4 waves in 2x2, each wave owns 64x64 (acc 4x4 of f32x4).
// Double-buffered K-loop: stage kt+1 into buf^1 (global_load_lds width=16),
// then compute kt from buf, then ONE __syncthreads per kt. The barrier's
// vmcnt(0) drain now waits on loads aged by a full compute phase instead of
// freshly-issued ones (R4's single-buffer drain was ~60% of runtime).
// LDS 64 KiB/block -> 2 blocks/CU. Triangular covering bx >= by; row-pass +
// col-pass (off-diag) covers every unordered pair; dups harmless (atomicMax).
__global__ __launch_bounds__(256, 2) void k_gemm_argmax(
    const uchar* __restrict__ xq, unsigned long long* __restrict__ best,
    int D, int T)
{
    // triangular mapping: p -> (by, bx), bx >= by
    const int p = blockIdx.x;
    const float tf = (float)T + 0.5f;
    int by = (int)(tf - sqrtf(tf * tf - 2.0f * (float)p));
    while (by > 0 && p < by * T - by * (by - 1) / 2) --by;
    while (p >= (by + 1) * T - (by + 1) * by / 2) ++by;
    const int bx = by + (p - (by * T - by * (by - 1) / 2));

    __shared__ uchar lds[2][(BM + BN) * BK];   // 2 x 32 KiB
    const int t    = threadIdx.x;
    const int lane = t & 63;
    const int wave = t >> 6;
    const int quad = lane >> 4;
    const int c16  = lane & 15;
    const int wrow = (wave >> 1) * 64;
    const int wcol = (wave & 1) * 64;
    const int m0   = by * BM;
    const int n0   = bx * BN;

    f32x4 acc[4][4] = {};

    // staging pattern: chunk ci = it*256+t -> row = ci>>3, stored chunk-col
    // c8s = t&7; global chunk-col = c8s ^ (row&7) (XOR swizzle on the global
    // side keeps global_load_lds lane-contiguity).
    const int row_s = t >> 3;
    const int c8s   = t & 7;

    // per-thread global byte offsets (row*D + swizzled col), kt added per iter
    int ag[4], bg[4], lo[4];
    #pragma unroll
    for (int it = 0; it < 4; ++it) {
        const int row  = it * 32 + row_s;
        const int gcol = (c8s ^ (row & 7)) * 16;
        ag[it] = (m0 + row) * 1024 + gcol;
        bg[it] = (n0 + row) * 1024 + gcol;
        lo[it] = (it * 256 + t) * 16;
    }

    // prologue: stage kt=0 into buf 0
    #pragma unroll
    for (int it = 0; it < 4; ++it) {
        __builtin_amdgcn_global_load_lds(
            (const __attribute__((address_space(1))) void*)(xq + ag[it]),
            (__attribute__((address_space(3))) void*)(&lds[0][0] + lo[it]), 16, 0, 0);
        __builtin_amdgcn_global_load_lds(
            (const __attribute__((address_space(1))) void*)(xq + bg[it]),
            (__attribute__((address_space(3))) void*)(&lds[0][BM * BK] + lo[it]), 16, 0, 0);
    }
    __syncthreads();

    const int swz = c16 & 7;
    for (int kt = 0; kt < 8; ++kt) {
        const int cur = kt & 1;
        // ---- stage kt+1 into the other buffer (issued before compute) ----
        if (kt < 7) {
            const int ko = (kt + 1) * BK;
            #pragma unroll
            for (int it = 0; it < 4; ++it) {
                __builtin_amdgcn_global_load_lds(
                    (const __attribute__((address_space(1))) void*)(xq + ag[it] + ko),
                    (__attribute__((address_space(3))) void*)(&lds[cur ^ 1][0] + lo[it]), 16, 0, 0);
                __builtin_amdgcn_global_load_lds(
                    (const __attribute__((address_space(1))) void*)(xq + bg[it] + ko),
                    (__attribute__((address_space(3))) void*)(&lds[cur ^ 1][BM * BK] + lo[it]), 16, 0, 0);
            }
        }
        // ---- compute kt from lds[cur] ----
        const uchar* Al = &lds[cur][0];
        const uchar* Bl = &lds[cur][BM * BK];
        #pragma unroll
        for (int ks = 0; ks < 4; ++ks) {     // 4 x K=32 per BK=128
            i64 a[4], b[4];
            // lane's k-group: k = ks*32 + quad*8 -> chunk (ks*2 + quad/2), half (quad&1)
            const int cc = (((ks * 2 + (quad >> 1)) ^ swz) * 16) + (quad & 1) * 8;
            #pragma unroll
            for (int i = 0; i < 4; ++i)
                a[i] = *(const i64*)(Al + (wrow + i * 16 + c16) * BK + cc);
            #pragma unroll
            for (int j = 0; j < 4; ++j)
                b[j] = *(const i64*)(Bl + (wcol + j * 16 + c16) * BK + cc);
            #pragma unroll
            for (int i = 0; i < 4; ++i)
                #pragma unroll
                for (int j = 0; j < 4; ++j)
                    acc[i][j] = __builtin_amdgcn_mfma_f32_16x16x32_fp8_fp8(
                        a[i], b[j], acc[i][j], 0, 0, 0);
        }
        __syncthreads();   // single barrier per kt; drains well-aged loads
    }

    // ---- row-wise argmax (this wave's 64 rows, over its 64 cols) ----
    // C/D layout (m89-verified, dtype-independent): col = lane&15, row = quad*4 + reg.
    #pragma unroll
    for (int i = 0; i < 4; ++i) {
        #pragma unroll
        for (int r = 0; r < 4; ++r) {
            const int grow = m0 + wrow + i * 16 + quad * 4 + r;
            float v = -3.0f; unsigned c = 0xFFFFFFFFu;
            #pragma unroll
            for (int j = 0; j < 4; ++j) {
                const int col = n0 + wcol + j * 16 + c16;
                const float val = acc[i][j][r];
                if (col != grow && (val > v || (val == v && (unsigned)col < c))) {
                    v = val; c = (unsigned)col;
                }
            }
            // reduce across the quad's 16 lanes (one row lives in one quad)
            for (int off = 8; off; off >>= 1) {
                const float    ov = __shfl_xor(v, off);
                const unsigned oc = (unsigned)__shfl_xor((int)c, off);
                if (ov > v || (ov == v && oc < c)) { v = ov; c = oc; }
            }
            if (c16 == 0) atomicMax(best + grow, pack_key(v, c));
        }
    }

    // ---- col-wise argmax (off-diagonal blocks only) ----
    if (bx != by) {
        #pragma unroll
        for (int j = 0; j < 4; ++j) {
            const int gcol = n0 + wcol + j * 16 + c16;
            float v = -3.0f; unsigned c = 0xFFFFFFFFu;
            #pragma unroll
            for (int i = 0; i < 4; ++i) {
                #pragma unroll
                for (int r = 0; r < 4; ++r) {
                    const int grow = m0 + wrow + i * 16 + quad * 4 + r;
                    const float val = acc[i][j][r];
                    if (val > v || (val == v && (unsigned)grow < c)) {
                        v = val; c = (unsigned)grow;
                    }
                }
            }
            // reduce across the 4 quads (lanes sharing c16): xor 16, 32
            for (int off = 32; off >= 16; off >>= 1) {
                const float    ov = __shfl_xor(v, off);
                const unsigned oc = (unsigned)__shfl_xor((int)c, off);
                if (ov > v || (ov == v && oc < c)) { v = ov; c = oc; }
            }
            if (quad == 0) atomicMax(best + gcol, pack_key(v, c));
        }
    }
}

// ---------------- 3) pairwise distance + log -> 256 padded partials ---------
__global__ __launch_bounds__(256) void k_dist(
    const float* __restrict__ in, const float* __restrict__ norms,
    const unsigned long long* __restrict__ best, float* __restrict__ psum, int D)
{
    const int row = blockIdx.x;
    const int t = threadIdx.x;
    const unsigned long long key = best[row];
    const int nb = (int)(~(unsigned)key);        // recover neighbor index
    const float invi = 1.0f / fmaxf(norms[row], KEPS);
    const float invj = 1.0f / fmaxf(norms[nb], KEPS);
    const float4* xi = (const float4*)(in + (size_t)row * D);
    const float4* xj = (const float4*)(in + (size_t)nb * D);
    const float4 a = xi[t], b = xj[t];
    const float dx = a.x * invi - b.x * invj + KEPS;
    const float dy = a.y * invi - b.y * invj + KEPS;
    const float dz = a.z * invi - b.z * invj + KEPS;
    const float dw = a.w * invi - b.w * invj + KEPS;
    float ss = dx*dx + dy*dy + dz*dz + dw*dw;
    for (int off = 32; off; off >>= 1) ss += __shfl_down(ss, off);
    __shared__ float red[4];
    const int lane = t & 63, wave = t >> 6;
    if (lane == 0) red[wave] = ss;
    __syncthreads();
    if (t == 0) {
        const float tot = red[0] + red[1] + red[2] + red[3];
        // scatter over 256 cache-line-padded slots: 64 atomics/slot, no hotspot
        atomicAdd(psum + (row & 255) * 16, logf(sqrtf(tot) + KEPS));
    }
}

// ---------------- 4) finalize: reduce 256 partials --------------------------
__global__ void k_final(const float* __restrict__ psum, float* __restrict__ out, float invN)
{
    const int t = threadIdx.x;                   // 64 threads
    float s = psum[t * 16] + psum[(t + 64) * 16]
            + psum[(t + 128) * 16] + psum[(t + 192) * 16];
    for (int off = 32; off; off >>= 1) s += __shfl_down(s, off);
    if (t == 0) out[0] = -s * invN;
}

extern "C" void kernel_launch(void* const* d_in, const int* in_sizes, int n_in,
                              void* d_out, int out_size, void* d_ws, size_t ws_size,
                              hipStream_t stream)
{
    const float* in = (const float*)d_in[0];
    const int D = 1024;
    const int N = in_sizes[0] / D;               // 16384

    char* ws = (char*)d_ws;
    uchar* xq = (uchar*)ws;                                      // N*D = 16 MiB
    size_t off = (size_t)N * D;
    float* norms = (float*)(ws + off);           off += (size_t)N * 4;
    unsigned long long* best = (unsigned long long*)(ws + off); off += (size_t)N * 8;
    float* psum = (float*)(ws + off);            // 256 slots x 16 floats
    float* out = (float*)d_out;

    k_normalize<<<N, 256, 0, stream>>>(in, xq, norms, best, psum, D);
    const int T = N / BM;                        // 128 tiles per dim
    const int P = T * (T + 1) / 2;               // 8256 upper-tri blocks
    k_gemm_argmax<<<P, 256, 0, stream>>>(xq, best, D, T);
    k_dist<<<N, 256, 0, stream>>>(in, norms, best, psum, D);
    k_final<<<1, 64, 0, stream>>>(psum, out, 1.0f / (float)N);
}

// Round 9
// 411.724 us; speedup vs baseline: 2.3146x; 1.2843x over previous
//
#include <hip/hip_runtime.h>

typedef float f32x4 __attribute__((ext_vector_type(4)));
typedef unsigned char uchar;
typedef long i64;

#define KEPS 1e-8f
#define BM 128
#define BN 128
#define BK 64    // fp8 bytes == elements; 16 K-iterations over D=1024

// ---------------- 1) row L2-normalize: fp32 norms + fp8 e4m3 copy -----------
__global__ __launch_bounds__(256) void k_normalize(
    const float* __restrict__ in, uchar* __restrict__ xq,
    float* __restrict__ norms, unsigned long long* __restrict__ best,
    float* __restrict__ psum, int D)
{
    const int row = blockIdx.x;
    const int t = threadIdx.x;
    const float4* inr = (const float4*)(in + (size_t)row * D);
    float4 v = inr[t];                       // D=1024 -> 256 float4
    float ss = v.x*v.x + v.y*v.y + v.z*v.z + v.w*v.w;
    for (int off = 32; off; off >>= 1) ss += __shfl_down(ss, off);
    __shared__ float red[4];
    const int lane = t & 63, wave = t >> 6;
    if (lane == 0) red[wave] = ss;
    __syncthreads();
    const float total = red[0] + red[1] + red[2] + red[3];
    const float nrm = sqrtf(total);
    const float inv = 1.0f / fmaxf(nrm, KEPS);
    unsigned r = 0;
    r = __builtin_amdgcn_cvt_pk_fp8_f32(v.x * inv, v.y * inv, r, 0);
    r = __builtin_amdgcn_cvt_pk_fp8_f32(v.z * inv, v.w * inv, r, 1);
    ((unsigned*)(xq + (size_t)row * D))[t] = r;
    if (t == 0) {
        norms[row] = nrm;
        best[row] = 0ull;                    // any real packed key beats 0
    }
    if (row < 256 && t == 1) psum[row * 16] = 0.0f;   // cache-line-padded partials
}

__device__ __forceinline__ unsigned long long pack_key(float v, unsigned idx)
{
    unsigned ub = __float_as_uint(v);
    ub = (ub & 0x80000000u) ? ~ub : (ub | 0x80000000u); // monotonic map
    return ((unsigned long long)ub << 32) | (unsigned long long)(~idx);
}

// ---------------- 2) x x^T triangular fp8 GEMM, dbuf LDS, 4 blocks/CU -------
// BM=BN=128, BK=64, 4 waves in 2x2, each wave owns 64x64 (acc 4x4 of f32x4).
// Double-buffered: 2 x 16 KiB LDS -> 32 KiB/block -> 4 blocks/CU (128 KiB).
// __launch_bounds__(256,4) caps regs at 128/wave (64 AGPR acc + ~55 VGPR) so
// 16 waves/CU co-reside: when one block drains its barrier, three others
// still feed the MFMA pipes (cross-block latency hiding — R7's missing 65%).
// NOTE: global_load_lds's `offset` param must be a front-end literal — the
// K-advance goes into the pointer instead (folded after full unroll).
// XOR swizzle (row ^ row>>2)&3 at 16B granularity: staging stays
// lane-contiguous (swizzle applied to the *global* column), ds_read_b64
// conflicts reduced to free 2-way.
// Triangular covering bx >= by; row-pass + col-pass (off-diag) covers every
// unordered pair; duplicates harmless under idempotent atomicMax.
__global__ __launch_bounds__(256, 4) void k_gemm_argmax(
    const uchar* __restrict__ xq, unsigned long long* __restrict__ best,
    int T)
{
    // triangular mapping: p -> (by, bx), bx >= by
    const int p = blockIdx.x;
    const float tf = (float)T + 0.5f;
    int by = (int)(tf - sqrtf(tf * tf - 2.0f * (float)p));
    while (by > 0 && p < by * T - by * (by - 1) / 2) --by;
    while (p >= (by + 1) * T - (by + 1) * by / 2) ++by;
    const int bx = by + (p - (by * T - by * (by - 1) / 2));

    __shared__ uchar lds[2][(BM + BN) * BK];   // 2 x 16 KiB
    const int t    = threadIdx.x;
    const int lane = t & 63;
    const int wave = t >> 6;
    const int quad = lane >> 4;
    const int c16  = lane & 15;
    const int wrow = (wave >> 1) * 64;
    const int wcol = (wave & 1) * 64;
    const int m0   = by * BM;
    const int n0   = bx * BN;

    f32x4 acc[4][4] = {};

    // staging: thread t owns stored chunk c = t (rows 0..63) and c = t + 256
    // (rows 64..127) of each panel; stored col = t&3, global col swizzled.
    const int row_s = t >> 2;
    const int col_s = t & 3;
    const int gsw = (col_s ^ ((row_s ^ (row_s >> 2)) & 3)) * 16;  // byte col
    // note swz(row+64) == swz(row), so the same gsw serves both halves
    const uchar* aP0 = xq + (size_t)(m0 + row_s) * 1024 + gsw;
    const uchar* bP0 = xq + (size_t)(n0 + row_s) * 1024 + gsw;
    const uchar* aP1 = aP0 + 64 * 1024;
    const uchar* bP1 = bP0 + 64 * 1024;
    const int l16 = t * 16;

#define STAGE(buf, koff)                                                              \
    do {                                                                              \
        __builtin_amdgcn_global_load_lds(                                             \
            (const __attribute__((address_space(1))) void*)(aP0 + (koff)),            \
            (__attribute__((address_space(3))) void*)(&lds[buf][0] + l16), 16, 0, 0); \
        __builtin_amdgcn_global_load_lds(                                             \
            (const __attribute__((address_space(1))) void*)(aP1 + (koff)),            \
            (__attribute__((address_space(3))) void*)(&lds[buf][4096] + l16), 16, 0, 0); \
        __builtin_amdgcn_global_load_lds(                                             \
            (const __attribute__((address_space(1))) void*)(bP0 + (koff)),            \
            (__attribute__((address_space(3))) void*)(&lds[buf][8192] + l16), 16, 0, 0); \
        __builtin_amdgcn_global_load_lds(                                             \
            (const __attribute__((address_space(1))) void*)(bP1 + (koff)),            \
            (__attribute__((address_space(3))) void*)(&lds[buf][12288] + l16), 16, 0, 0); \
    } while (0)

    STAGE(0, 0);
    __syncthreads();

    #pragma unroll
    for (int kt = 0; kt < 16; ++kt) {
        const int cur = kt & 1;
        if (kt < 15) STAGE(cur ^ 1, (kt + 1) * BK);   // K-advance in pointer
        const uchar* Al = &lds[cur][0];
        const uchar* Bl = &lds[cur][8192];
        #pragma unroll
        for (int ks = 0; ks < 2; ++ks) {     // 2 x K=32 per BK=64
            i64 a[4], b[4];
            const int ccol = ks * 2 + (quad >> 1);    // 16B chunk col
            const int inner = (quad & 1) * 8;
            #pragma unroll
            for (int i = 0; i < 4; ++i) {
                const int row = wrow + i * 16 + c16;
                a[i] = *(const i64*)(Al + row * 64 +
                        ((ccol ^ ((row ^ (row >> 2)) & 3)) * 16) + inner);
            }
            #pragma unroll
            for (int j = 0; j < 4; ++j) {
                const int row = wcol + j * 16 + c16;
                b[j] = *(const i64*)(Bl + row * 64 +
                        ((ccol ^ ((row ^ (row >> 2)) & 3)) * 16) + inner);
            }
            #pragma unroll
            for (int i = 0; i < 4; ++i)
                #pragma unroll
                for (int j = 0; j < 4; ++j)
                    acc[i][j] = __builtin_amdgcn_mfma_f32_16x16x32_fp8_fp8(
                        a[i], b[j], acc[i][j], 0, 0, 0);
        }
        __syncthreads();
    }
#undef STAGE

    // ---- row-wise argmax (this wave's 64 rows, over its 64 cols) ----
    // C/D layout (m89-verified, dtype-independent): col = lane&15, row = quad*4 + reg.
    #pragma unroll
    for (int i = 0; i < 4; ++i) {
        #pragma unroll
        for (int r = 0; r < 4; ++r) {
            const int grow = m0 + wrow + i * 16 + quad * 4 + r;
            float v = -3.0f; unsigned c = 0xFFFFFFFFu;
            #pragma unroll
            for (int j = 0; j < 4; ++j) {
                const int col = n0 + wcol + j * 16 + c16;
                const float val = acc[i][j][r];
                if (col != grow && (val > v || (val == v && (unsigned)col < c))) {
                    v = val; c = (unsigned)col;
                }
            }
            // reduce across the quad's 16 lanes (one row lives in one quad)
            for (int off = 8; off; off >>= 1) {
                const float    ov = __shfl_xor(v, off);
                const unsigned oc = (unsigned)__shfl_xor((int)c, off);
                if (ov > v || (ov == v && oc < c)) { v = ov; c = oc; }
            }
            if (c16 == 0) atomicMax(best + grow, pack_key(v, c));
        }
    }

    // ---- col-wise argmax (off-diagonal blocks only) ----
    if (bx != by) {
        #pragma unroll
        for (int j = 0; j < 4; ++j) {
            const int gcol = n0 + wcol + j * 16 + c16;
            float v = -3.0f; unsigned c = 0xFFFFFFFFu;
            #pragma unroll
            for (int i = 0; i < 4; ++i) {
                #pragma unroll
                for (int r = 0; r < 4; ++r) {
                    const int grow = m0 + wrow + i * 16 + quad * 4 + r;
                    const float val = acc[i][j][r];
                    if (val > v || (val == v && (unsigned)grow < c)) {
                        v = val; c = (unsigned)grow;
                    }
                }
            }
            // reduce across the 4 quads (lanes sharing c16): xor 16, 32
            for (int off = 32; off >= 16; off >>= 1) {
                const float    ov = __shfl_xor(v, off);
                const unsigned oc = (unsigned)__shfl_xor((int)c, off);
                if (ov > v || (ov == v && oc < c)) { v = ov; c = oc; }
            }
            if (quad == 0) atomicMax(best + gcol, pack_key(v, c));
        }
    }
}

// ---------------- 3) pairwise distance + log -> 256 padded partials ---------
__global__ __launch_bounds__(256) void k_dist(
    const float* __restrict__ in, const float* __restrict__ norms,
    const unsigned long long* __restrict__ best, float* __restrict__ psum, int D)
{
    const int row = blockIdx.x;
    const int t = threadIdx.x;
    const unsigned long long key = best[row];
    const int nb = (int)(~(unsigned)key);        // recover neighbor index
    const float invi = 1.0f / fmaxf(norms[row], KEPS);
    const float invj = 1.0f / fmaxf(norms[nb], KEPS);
    const float4* xi = (const float4*)(in + (size_t)row * D);
    const float4* xj = (const float4*)(in + (size_t)nb * D);
    const float4 a = xi[t], b = xj[t];
    const float dx = a.x * invi - b.x * invj + KEPS;
    const float dy = a.y * invi - b.y * invj + KEPS;
    const float dz = a.z * invi - b.z * invj + KEPS;
    const float dw = a.w * invi - b.w * invj + KEPS;
    float ss = dx*dx + dy*dy + dz*dz + dw*dw;
    for (int off = 32; off; off >>= 1) ss += __shfl_down(ss, off);
    __shared__ float red[4];
    const int lane = t & 63, wave = t >> 6;
    if (lane == 0) red[wave] = ss;
    __syncthreads();
    if (t == 0) {
        const float tot = red[0] + red[1] + red[2] + red[3];
        // scatter over 256 cache-line-padded slots: 64 atomics/slot, no hotspot
        atomicAdd(psum + (row & 255) * 16, logf(sqrtf(tot) + KEPS));
    }
}

// ---------------- 4) finalize: reduce 256 partials --------------------------
__global__ void k_final(const float* __restrict__ psum, float* __restrict__ out, float invN)
{
    const int t = threadIdx.x;                   // 64 threads
    float s = psum[t * 16] + psum[(t + 64) * 16]
            + psum[(t + 128) * 16] + psum[(t + 192) * 16];
    for (int off = 32; off; off >>= 1) s += __shfl_down(s, off);
    if (t == 0) out[0] = -s * invN;
}

extern "C" void kernel_launch(void* const* d_in, const int* in_sizes, int n_in,
                              void* d_out, int out_size, void* d_ws, size_t ws_size,
                              hipStream_t stream)
{
    const float* in = (const float*)d_in[0];
    const int D = 1024;
    const int N = in_sizes[0] / D;               // 16384

    char* ws = (char*)d_ws;
    uchar* xq = (uchar*)ws;                                      // N*D = 16 MiB
    size_t off = (size_t)N * D;
    float* norms = (float*)(ws + off);           off += (size_t)N * 4;
    unsigned long long* best = (unsigned long long*)(ws + off); off += (size_t)N * 8;
    float* psum = (float*)(ws + off);            // 256 slots x 16 floats
    float* out = (float*)d_out;

    k_normalize<<<N, 256, 0, stream>>>(in, xq, norms, best, psum, D);
    const int T = N / BM;                        // 128 tiles per dim
    const int P = T * (T + 1) / 2;               // 8256 upper-tri blocks
    k_gemm_argmax<<<P, 256, 0, stream>>>(xq, best, T);
    k_dist<<<N, 256, 0, stream>>>(in, norms, best, psum, D);
    k_final<<<1, 64, 0, stream>>>(psum, out, 1.0f / (float)N);
}